// Round 2
// baseline (994.007 us; speedup 1.0000x reference)
//
#include <hip/hip_runtime.h>
#include <stdint.h>

#define NN 200000
#define NE 800000
#define FIN 128
#define NG 8000
#define EPSV 1e-5f

// ---- degree: deg[i] = count of edges with dst==i (as float) ----
__global__ void k_deg(const int* __restrict__ dst, float* __restrict__ deg) {
    int e = blockIdx.x * 256 + threadIdx.x;
    if (e < NE) atomicAdd(&deg[dst[e]], 1.0f);
}

// ---- dis = rsqrt(1 + deg), in place ----
__global__ void k_dis(float* __restrict__ d) {
    int n = blockIdx.x * 256 + threadIdx.x;
    if (n < NN) d[n] = rsqrtf(1.0f + d[n]);
}

// ---- graph start offsets from sorted batch ----
__global__ void k_starts(const int* __restrict__ batch, int* __restrict__ startg) {
    int n = blockIdx.x * 256 + threadIdx.x;
    if (n >= NN) return;
    int b = batch[n];
    int prev = (n == 0) ? -1 : batch[n - 1];
    for (int g = prev + 1; g <= b; ++g) startg[g] = n;
    if (n == NN - 1) {
        for (int g = b + 1; g <= NG; ++g) startg[g] = NN;
    }
}

// ---- per-graph per-channel instance-norm stats -> scale/shift ----
__global__ void k_stats(const float* __restrict__ x, const int* __restrict__ startg,
                        const float* __restrict__ nw, const float* __restrict__ nb,
                        float* __restrict__ scale, float* __restrict__ shift) {
    int g = blockIdx.x;
    int c = threadIdx.x;  // 128 threads
    int s = startg[g], e = startg[g + 1];
    float sum = 0.f, sq = 0.f;
    for (int n = s; n < e; ++n) {
        float v = x[n * FIN + c];
        sum += v; sq += v * v;
    }
    float cnt = (float)max(e - s, 1);
    float mean = sum / cnt;
    float var = sq / cnt - mean * mean;
    float istd = rsqrtf(fmaxf(var, 0.f) + EPSV);
    float w = nw[0], b = nb[0];
    scale[g * FIN + c] = istd * w;
    shift[g * FIN + c] = b - mean * istd * w;
}

// ---- conv1: p1 = ((x*scale+shift) @ W1) * dis   [C: 128 -> 32], 32 nodes/block ----
__global__ __launch_bounds__(256) void k_conv1(const float* __restrict__ x,
                                               const int* __restrict__ batch,
                                               const float* __restrict__ scale,
                                               const float* __restrict__ shift,
                                               const float* __restrict__ W1,
                                               const float* __restrict__ dis,
                                               float* __restrict__ p1) {
    __shared__ float sW[FIN * 32];   // 16 KB
    __shared__ float sx[32 * FIN];   // 16 KB
    int t = threadIdx.x;
    const float4* W4 = (const float4*)W1;
    for (int i = t; i < FIN * 32 / 4; i += 256) ((float4*)sW)[i] = W4[i];
    int base = blockIdx.x * 32;
    const float4* x4 = (const float4*)x;        // row stride 32 float4
    const float4* sc4 = (const float4*)scale;
    const float4* sh4 = (const float4*)shift;
    for (int i = t; i < 32 * 32; i += 256) {
        int nl = i >> 5, c4 = i & 31;
        int n = base + nl;
        int g = batch[n];
        float4 xv = x4[n * 32 + c4];
        float4 sc = sc4[g * 32 + c4];
        float4 sh = sh4[g * 32 + c4];
        float4 r;
        r.x = xv.x * sc.x + sh.x;
        r.y = xv.y * sc.y + sh.y;
        r.z = xv.z * sc.z + sh.z;
        r.w = xv.w * sc.w + sh.w;
        ((float4*)sx)[i] = r;   // sx[nl*128 + c4*4 ..]
    }
    __syncthreads();
    int k = t & 31, grp = t >> 5;  // grp in [0,8), 4 nodes each
    float acc[4] = {0.f, 0.f, 0.f, 0.f};
    for (int c = 0; c < FIN; ++c) {
        float w = sW[c * 32 + k];
#pragma unroll
        for (int q = 0; q < 4; ++q) acc[q] += sx[(grp * 4 + q) * FIN + c] * w;
    }
#pragma unroll
    for (int q = 0; q < 4; ++q) {
        int n = base + grp * 4 + q;
        p1[n * 32 + k] = acc[q] * dis[n];
    }
}

// ---- edge scatter, C=32: acc[dst] += p[src] ----
__global__ void k_scatter32(const int* __restrict__ src, const int* __restrict__ dst,
                            const float* __restrict__ p, float* __restrict__ acc) {
    int tid = blockIdx.x * 256 + threadIdx.x;
    int e = tid >> 5, c = tid & 31;
    if (e < NE) atomicAdd(&acc[dst[e] * 32 + c], p[src[e] * 32 + c]);
}

// ---- edge scatter, C=64 ----
__global__ void k_scatter64(const int* __restrict__ src, const int* __restrict__ dst,
                            const float* __restrict__ p, float* __restrict__ acc) {
    int tid = blockIdx.x * 256 + threadIdx.x;
    int e = tid >> 6, c = tid & 63;
    if (e < NE) atomicAdd(&acc[dst[e] * 64 + c], p[src[e] * 64 + c]);
}

// ---- finish conv1: h1 = relu(dis*(acc1+p1)+b1); p2 = h1*dis ----
__global__ void k_finish1(const float* __restrict__ p1, const float* __restrict__ acc1,
                          const float* __restrict__ dis, const float* __restrict__ b1,
                          float* __restrict__ p2) {
    int tid = blockIdx.x * 256 + threadIdx.x;
    if (tid >= NN * 32) return;
    int n = tid >> 5, c = tid & 31;
    float d = dis[n];
    float h = fmaxf(d * (acc1[tid] + p1[tid]) + b1[c], 0.f);
    p2[tid] = h * d;
}

// ---- conv2: a2 = dis*(acc2+p2); h2 = relu(a2@W2+b2); p3 = h2*dis  [32->64], 16 nodes/block ----
__global__ __launch_bounds__(256) void k_conv2(const float* __restrict__ p2,
                                               const float* __restrict__ acc2,
                                               const float* __restrict__ dis,
                                               const float* __restrict__ W2,
                                               const float* __restrict__ b2v,
                                               float* __restrict__ p3) {
    __shared__ float sW[32 * 64];  // 8 KB
    __shared__ float sa[16 * 32];  // 2 KB
    int t = threadIdx.x;
    const float4* W4 = (const float4*)W2;
    for (int i = t; i < 32 * 64 / 4; i += 256) ((float4*)sW)[i] = W4[i];
    int base = blockIdx.x * 16;
    for (int i = t; i < 16 * 32; i += 256) {
        int nl = i >> 5, c = i & 31;
        int n = base + nl;
        sa[i] = dis[n] * (acc2[n * 32 + c] + p2[n * 32 + c]);
    }
    __syncthreads();
    int k = t & 63, grp = t >> 6;  // grp in [0,4), 4 nodes each
    float acc[4] = {0.f, 0.f, 0.f, 0.f};
    for (int c = 0; c < 32; ++c) {
        float w = sW[c * 64 + k];
#pragma unroll
        for (int q = 0; q < 4; ++q) acc[q] += sa[(grp * 4 + q) * 32 + c] * w;
    }
    float bb = b2v[k];
#pragma unroll
    for (int q = 0; q < 4; ++q) {
        int n = base + grp * 4 + q;
        float h = fmaxf(acc[q] + bb, 0.f);
        p3[n * 64 + k] = h * dis[n];
    }
}

// ---- conv3 + fused max-pool: o = relu(dis*(acc3+p3)@W3+b3); pooled = max  [64->128], 8 nodes/block ----
__global__ __launch_bounds__(256) void k_conv3(const float* __restrict__ p3,
                                               const float* __restrict__ acc3,
                                               const float* __restrict__ dis,
                                               const float* __restrict__ W3,
                                               const float* __restrict__ b3v,
                                               const int* __restrict__ batch,
                                               unsigned int* __restrict__ pooled) {
    __shared__ float sW[64 * 128];  // 32 KB
    __shared__ float sa[8 * 64];    // 2 KB
    int t = threadIdx.x;
    const float4* W4 = (const float4*)W3;
    for (int i = t; i < 64 * 128 / 4; i += 256) ((float4*)sW)[i] = W4[i];
    int base = blockIdx.x * 8;
    for (int i = t; i < 8 * 64; i += 256) {
        int nl = i >> 6, c = i & 63;
        int n = base + nl;
        sa[i] = dis[n] * (acc3[n * 64 + c] + p3[n * 64 + c]);
    }
    __syncthreads();
    int k = t & 127, half = t >> 7;  // half in {0,1}, 4 nodes each
    float acc[4] = {0.f, 0.f, 0.f, 0.f};
    for (int c = 0; c < 64; ++c) {
        float w = sW[c * 128 + k];
#pragma unroll
        for (int q = 0; q < 4; ++q) acc[q] += sa[(half * 4 + q) * 64 + c] * w;
    }
    float bb = b3v[k];
#pragma unroll
    for (int q = 0; q < 4; ++q) {
        int n = base + half * 4 + q;
        float o = fmaxf(acc[q] + bb, 0.f);
        atomicMax(&pooled[batch[n] * 128 + k], __float_as_uint(o));  // o >= 0, bit-order == value-order
    }
}

// ---- lin1: mid = relu(pooled @ lin1_W + b), 8 graphs/block ----
__global__ __launch_bounds__(256) void k_lin1(const float* __restrict__ pooled,
                                              const float* __restrict__ W,
                                              const float* __restrict__ bias,
                                              float* __restrict__ mid) {
    __shared__ float sp[8 * 128];  // 4 KB
    int t = threadIdx.x;
    int base = blockIdx.x * 8;
    for (int i = t; i < 8 * 128; i += 256) sp[i] = pooled[base * 128 + i];
    __syncthreads();
    float acc[8] = {0.f, 0.f, 0.f, 0.f, 0.f, 0.f, 0.f, 0.f};
    for (int c = 0; c < 128; ++c) {
        float w = W[c * 256 + t];
#pragma unroll
        for (int gl = 0; gl < 8; ++gl) acc[gl] += sp[gl * 128 + c] * w;
    }
    float bb = bias[t];
#pragma unroll
    for (int gl = 0; gl < 8; ++gl) mid[(base + gl) * 256 + t] = fmaxf(acc[gl] + bb, 0.f);
}

// ---- lin2: out = mid @ lin2_W + b  (fp32 store), 16 graphs/block ----
__global__ __launch_bounds__(128) void k_lin2(const float* __restrict__ mid,
                                              const float* __restrict__ W,
                                              const float* __restrict__ bias,
                                              float* __restrict__ out) {
    __shared__ float sm[16 * 256];  // 16 KB
    int t = threadIdx.x;
    int base = blockIdx.x * 16;
    for (int i = t; i < 16 * 256; i += 128) sm[i] = mid[base * 256 + i];
    __syncthreads();
    float acc[16];
#pragma unroll
    for (int i = 0; i < 16; ++i) acc[i] = 0.f;
    for (int c = 0; c < 256; ++c) {
        float w = W[c * 128 + t];
#pragma unroll
        for (int gl = 0; gl < 16; ++gl) acc[gl] += sm[gl * 256 + c] * w;
    }
    float bb = bias[t];
#pragma unroll
    for (int gl = 0; gl < 16; ++gl)
        out[(base + gl) * 128 + t] = acc[gl] + bb;
}

extern "C" void kernel_launch(void* const* d_in, const int* in_sizes, int n_in,
                              void* d_out, int out_size, void* d_ws, size_t ws_size,
                              hipStream_t stream) {
    (void)in_sizes; (void)n_in; (void)out_size; (void)ws_size;
    const float* x   = (const float*)d_in[0];
    const int* ei    = (const int*)d_in[1];
    const int* src = ei;
    const int* dst = ei + NE;
    const int* batch = (const int*)d_in[2];
    const float* nw  = (const float*)d_in[3];
    const float* nb  = (const float*)d_in[4];
    const float* W1  = (const float*)d_in[5];
    const float* b1  = (const float*)d_in[6];
    const float* W2  = (const float*)d_in[7];
    const float* b2  = (const float*)d_in[8];
    const float* W3  = (const float*)d_in[9];
    const float* b3  = (const float*)d_in[10];
    const float* l1W = (const float*)d_in[11];
    const float* l1b = (const float*)d_in[12];
    const float* l2W = (const float*)d_in[13];
    const float* l2b = (const float*)d_in[14];
    float* out = (float*)d_out;

    char* wsp = (char*)d_ws;
    float* dis    = (float*)wsp; wsp += (size_t)NN * 4;
    int*   startg = (int*)wsp;   wsp += (size_t)(NG + 1) * 4;
    wsp += ((16 - ((uintptr_t)wsp & 15)) & 15);
    float* scale  = (float*)wsp; wsp += (size_t)NG * 128 * 4;   // later: pooled
    float* shift  = (float*)wsp; wsp += (size_t)NG * 128 * 4;
    float* regionA = (float*)wsp; wsp += (size_t)NN * 64 * 4;   // p1|acc1, later p3
    float* regionB = (float*)wsp; wsp += (size_t)NN * 64 * 4;   // p2|acc2, later acc3, later mid

    float* p1   = regionA;
    float* acc1 = regionA + (size_t)NN * 32;
    float* p2   = regionB;
    float* acc2 = regionB + (size_t)NN * 32;
    float* p3   = regionA;
    float* acc3 = regionB;
    float* pooled = scale;    // scale/shift dead after k_conv1
    float* mid    = regionB;  // acc3 dead after k_conv3

    hipMemsetAsync(dis, 0, (size_t)NN * 4, stream);
    k_deg<<<(NE + 255) / 256, 256, 0, stream>>>(dst, dis);
    k_dis<<<(NN + 255) / 256, 256, 0, stream>>>(dis);
    k_starts<<<(NN + 255) / 256, 256, 0, stream>>>(batch, startg);
    k_stats<<<NG, 128, 0, stream>>>(x, startg, nw, nb, scale, shift);

    k_conv1<<<NN / 32, 256, 0, stream>>>(x, batch, scale, shift, W1, dis, p1);
    hipMemsetAsync(acc1, 0, (size_t)NN * 32 * 4, stream);
    k_scatter32<<<NE * 32 / 256, 256, 0, stream>>>(src, dst, p1, acc1);
    k_finish1<<<NN * 32 / 256, 256, 0, stream>>>(p1, acc1, dis, b1, p2);

    hipMemsetAsync(acc2, 0, (size_t)NN * 32 * 4, stream);
    k_scatter32<<<NE * 32 / 256, 256, 0, stream>>>(src, dst, p2, acc2);
    k_conv2<<<NN / 16, 256, 0, stream>>>(p2, acc2, dis, W2, b2, p3);

    hipMemsetAsync(acc3, 0, (size_t)NN * 64 * 4, stream);
    k_scatter64<<<NE * 64 / 256, 256, 0, stream>>>(src, dst, p3, acc3);
    hipMemsetAsync(pooled, 0, (size_t)NG * 128 * 4, stream);
    k_conv3<<<NN / 8, 256, 0, stream>>>(p3, acc3, dis, W3, b3, batch, (unsigned int*)pooled);

    k_lin1<<<NG / 8, 256, 0, stream>>>(pooled, l1W, l1b, mid);
    k_lin2<<<NG / 16, 128, 0, stream>>>(mid, l2W, l2b, out);
}

// Round 3
// 681.701 us; speedup vs baseline: 1.4581x; 1.4581x over previous
//
#include <hip/hip_runtime.h>
#include <stdint.h>

#define NN 200000
#define NE 800000
#define FIN 128
#define NG 8000
#define EPSV 1e-5f
#define NBS ((NN + 255) / 256)   // 782 scan blocks

// ---- int degree histogram over dst ----
__global__ void k_cnt(const int* __restrict__ dst, int* __restrict__ cnt) {
    int e = blockIdx.x * 256 + threadIdx.x;
    if (e < NE) atomicAdd(&cnt[dst[e]], 1);
}

// ---- per-256-chunk sums ----
__global__ void k_blocksum(const int* __restrict__ cnt, int* __restrict__ bsum) {
    __shared__ int sh[256];
    int b = blockIdx.x, t = threadIdx.x;
    int idx = b * 256 + t;
    sh[t] = (idx < NN) ? cnt[idx] : 0;
    __syncthreads();
    for (int o = 128; o > 0; o >>= 1) {
        if (t < o) sh[t] += sh[t + o];
        __syncthreads();
    }
    if (t == 0) bsum[b] = sh[0];
}

// ---- single-block scan of chunk sums -> exclusive prefixes ----
__global__ __launch_bounds__(1024) void k_scanb(const int* __restrict__ bsum, int* __restrict__ bpre) {
    __shared__ int sh[1024];
    int t = threadIdx.x;
    int v = (t < NBS) ? bsum[t] : 0;
    sh[t] = v;
    __syncthreads();
    for (int o = 1; o < 1024; o <<= 1) {
        int add = (t >= o) ? sh[t - o] : 0;
        __syncthreads();
        sh[t] += add;
        __syncthreads();
    }
    if (t < NBS) bpre[t] = sh[t] - v;  // exclusive
}

// ---- per-chunk scan + offset -> rowstart (exclusive) ----
__global__ void k_scanchunk(const int* __restrict__ cnt, const int* __restrict__ bpre,
                            int* __restrict__ rowstart) {
    __shared__ int sh[256];
    int b = blockIdx.x, t = threadIdx.x;
    int idx = b * 256 + t;
    int v = (idx < NN) ? cnt[idx] : 0;
    sh[t] = v;
    __syncthreads();
    for (int o = 1; o < 256; o <<= 1) {
        int add = (t >= o) ? sh[t - o] : 0;
        __syncthreads();
        sh[t] += add;
        __syncthreads();
    }
    if (idx < NN) rowstart[idx] = bpre[b] + sh[t] - v;
    if (idx == 0) rowstart[NN] = NE;
}

// ---- dis = rsqrt(1+deg), IN PLACE over cnt (int -> float reinterpret) ----
__global__ void k_dis(int* __restrict__ cnt) {
    int n = blockIdx.x * 256 + threadIdx.x;
    if (n < NN) {
        float d = rsqrtf(1.0f + (float)cnt[n]);
        ((float*)cnt)[n] = d;
    }
}

// ---- fill CSR: csr[pos] = src, bucketed by dst ----
__global__ void k_fill(const int* __restrict__ src, const int* __restrict__ dst,
                       int* __restrict__ cursor, int* __restrict__ csr) {
    int e = blockIdx.x * 256 + threadIdx.x;
    if (e < NE) {
        int pos = atomicAdd(&cursor[dst[e]], 1);
        csr[pos] = src[e];
    }
}

// ---- graph start offsets from sorted batch ----
__global__ void k_starts(const int* __restrict__ batch, int* __restrict__ startg) {
    int n = blockIdx.x * 256 + threadIdx.x;
    if (n >= NN) return;
    int b = batch[n];
    int prev = (n == 0) ? -1 : batch[n - 1];
    for (int g = prev + 1; g <= b; ++g) startg[g] = n;
    if (n == NN - 1) {
        for (int g = b + 1; g <= NG; ++g) startg[g] = NN;
    }
}

// ---- per-graph per-channel instance-norm stats -> scale/shift ----
__global__ void k_stats(const float* __restrict__ x, const int* __restrict__ startg,
                        const float* __restrict__ nw, const float* __restrict__ nb,
                        float* __restrict__ scale, float* __restrict__ shift) {
    int g = blockIdx.x;
    int c = threadIdx.x;  // 128 threads
    int s = startg[g], e = startg[g + 1];
    float sum = 0.f, sq = 0.f;
    for (int n = s; n < e; ++n) {
        float v = x[n * FIN + c];
        sum += v; sq += v * v;
    }
    float cnt = (float)max(e - s, 1);
    float mean = sum / cnt;
    float var = sq / cnt - mean * mean;
    float istd = rsqrtf(fmaxf(var, 0.f) + EPSV);
    float w = nw[0], b = nb[0];
    scale[g * FIN + c] = istd * w;
    shift[g * FIN + c] = b - mean * istd * w;
}

// ---- conv1: p1 = ((x*scale+shift) @ W1) * dis   [128 -> 32], 32 nodes/block ----
__global__ __launch_bounds__(256) void k_conv1(const float* __restrict__ x,
                                               const int* __restrict__ batch,
                                               const float* __restrict__ scale,
                                               const float* __restrict__ shift,
                                               const float* __restrict__ W1,
                                               const float* __restrict__ dis,
                                               float* __restrict__ p1) {
    __shared__ float sW[FIN * 32];   // 16 KB
    __shared__ float sx[32 * FIN];   // 16 KB
    int t = threadIdx.x;
    const float4* W4 = (const float4*)W1;
    for (int i = t; i < FIN * 32 / 4; i += 256) ((float4*)sW)[i] = W4[i];
    int base = blockIdx.x * 32;
    const float4* x4 = (const float4*)x;
    const float4* sc4 = (const float4*)scale;
    const float4* sh4 = (const float4*)shift;
    for (int i = t; i < 32 * 32; i += 256) {
        int nl = i >> 5, c4 = i & 31;
        int n = base + nl;
        int g = batch[n];
        float4 xv = x4[n * 32 + c4];
        float4 sc = sc4[g * 32 + c4];
        float4 sh = sh4[g * 32 + c4];
        float4 r;
        r.x = xv.x * sc.x + sh.x;
        r.y = xv.y * sc.y + sh.y;
        r.z = xv.z * sc.z + sh.z;
        r.w = xv.w * sc.w + sh.w;
        ((float4*)sx)[i] = r;
    }
    __syncthreads();
    int k = t & 31, grp = t >> 5;
    float acc[4] = {0.f, 0.f, 0.f, 0.f};
    for (int c = 0; c < FIN; ++c) {
        float w = sW[c * 32 + k];
#pragma unroll
        for (int q = 0; q < 4; ++q) acc[q] += sx[(grp * 4 + q) * FIN + c] * w;
    }
#pragma unroll
    for (int q = 0; q < 4; ++q) {
        int n = base + grp * 4 + q;
        p1[n * 32 + k] = acc[q] * dis[n];
    }
}

// ---- gather1 (C=32) + conv1 epilogue: p2 = relu(dis*(self+neigh)+b1)*dis ----
__global__ __launch_bounds__(256) void k_gather1(const float* __restrict__ p1,
                                                 const int* __restrict__ rowstart,
                                                 const int* __restrict__ csr,
                                                 const float* __restrict__ dis,
                                                 const float* __restrict__ b1,
                                                 float* __restrict__ p2) {
    int tid = blockIdx.x * 256 + threadIdx.x;
    int n = tid >> 5, c = tid & 31;
    int s = rowstart[n], e = rowstart[n + 1];
    float agg = p1[tid];  // self-loop term (p = h*dis already)
    int j = s;
    for (; j + 1 < e; j += 2) {
        int s0 = csr[j], s1 = csr[j + 1];
        float v0 = p1[s0 * 32 + c];
        float v1 = p1[s1 * 32 + c];
        agg += v0 + v1;
    }
    if (j < e) agg += p1[csr[j] * 32 + c];
    float d = dis[n];
    float h = fmaxf(d * agg + b1[c], 0.f);
    p2[tid] = h * d;
}

// ---- gather2 (C=32): a2 = dis*(self+neigh) ----
__global__ __launch_bounds__(256) void k_gather2(const float* __restrict__ p2,
                                                 const int* __restrict__ rowstart,
                                                 const int* __restrict__ csr,
                                                 const float* __restrict__ dis,
                                                 float* __restrict__ a2) {
    int tid = blockIdx.x * 256 + threadIdx.x;
    int n = tid >> 5, c = tid & 31;
    int s = rowstart[n], e = rowstart[n + 1];
    float agg = p2[tid];
    int j = s;
    for (; j + 1 < e; j += 2) {
        int s0 = csr[j], s1 = csr[j + 1];
        float v0 = p2[s0 * 32 + c];
        float v1 = p2[s1 * 32 + c];
        agg += v0 + v1;
    }
    if (j < e) agg += p2[csr[j] * 32 + c];
    a2[tid] = dis[n] * agg;
}

// ---- gather3 (C=64): a3 = dis*(self+neigh) ----
__global__ __launch_bounds__(256) void k_gather3(const float* __restrict__ p3,
                                                 const int* __restrict__ rowstart,
                                                 const int* __restrict__ csr,
                                                 const float* __restrict__ dis,
                                                 float* __restrict__ a3) {
    int tid = blockIdx.x * 256 + threadIdx.x;
    int n = tid >> 6, c = tid & 63;
    int s = rowstart[n], e = rowstart[n + 1];
    float agg = p3[tid];
    int j = s;
    for (; j + 1 < e; j += 2) {
        int s0 = csr[j], s1 = csr[j + 1];
        float v0 = p3[s0 * 64 + c];
        float v1 = p3[s1 * 64 + c];
        agg += v0 + v1;
    }
    if (j < e) agg += p3[csr[j] * 64 + c];
    a3[tid] = dis[n] * agg;
}

// ---- conv2: h2 = relu(a2@W2+b2); p3 = h2*dis  [32->64], 16 nodes/block ----
__global__ __launch_bounds__(256) void k_conv2(const float* __restrict__ a2,
                                               const float* __restrict__ dis,
                                               const float* __restrict__ W2,
                                               const float* __restrict__ b2v,
                                               float* __restrict__ p3) {
    __shared__ float sW[32 * 64];  // 8 KB
    __shared__ float sa[16 * 32];  // 2 KB
    int t = threadIdx.x;
    const float4* W4 = (const float4*)W2;
    for (int i = t; i < 32 * 64 / 4; i += 256) ((float4*)sW)[i] = W4[i];
    int base = blockIdx.x * 16;
    for (int i = t; i < 16 * 32; i += 256) sa[i] = a2[base * 32 + i];
    __syncthreads();
    int k = t & 63, grp = t >> 6;
    float acc[4] = {0.f, 0.f, 0.f, 0.f};
    for (int c = 0; c < 32; ++c) {
        float w = sW[c * 64 + k];
#pragma unroll
        for (int q = 0; q < 4; ++q) acc[q] += sa[(grp * 4 + q) * 32 + c] * w;
    }
    float bb = b2v[k];
#pragma unroll
    for (int q = 0; q < 4; ++q) {
        int n = base + grp * 4 + q;
        float h = fmaxf(acc[q] + bb, 0.f);
        p3[n * 64 + k] = h * dis[n];
    }
}

// ---- conv3 + fused max-pool: o = relu(a3@W3+b3); pooled = max  [64->128], 8 nodes/block ----
__global__ __launch_bounds__(256) void k_conv3(const float* __restrict__ a3,
                                               const float* __restrict__ W3,
                                               const float* __restrict__ b3v,
                                               const int* __restrict__ batch,
                                               unsigned int* __restrict__ pooled) {
    __shared__ float sW[64 * 128];  // 32 KB
    __shared__ float sa[8 * 64];    // 2 KB
    int t = threadIdx.x;
    const float4* W4 = (const float4*)W3;
    for (int i = t; i < 64 * 128 / 4; i += 256) ((float4*)sW)[i] = W4[i];
    int base = blockIdx.x * 8;
    for (int i = t; i < 8 * 64; i += 256) sa[i] = a3[base * 64 + i];
    __syncthreads();
    int k = t & 127, half = t >> 7;
    float acc[4] = {0.f, 0.f, 0.f, 0.f};
    for (int c = 0; c < 64; ++c) {
        float w = sW[c * 128 + k];
#pragma unroll
        for (int q = 0; q < 4; ++q) acc[q] += sa[(half * 4 + q) * 64 + c] * w;
    }
    float bb = b3v[k];
#pragma unroll
    for (int q = 0; q < 4; ++q) {
        int n = base + half * 4 + q;
        float o = fmaxf(acc[q] + bb, 0.f);
        atomicMax(&pooled[batch[n] * 128 + k], __float_as_uint(o));  // o >= 0
    }
}

// ---- lin1: mid = relu(pooled @ lin1_W + b), 8 graphs/block ----
__global__ __launch_bounds__(256) void k_lin1(const float* __restrict__ pooled,
                                              const float* __restrict__ W,
                                              const float* __restrict__ bias,
                                              float* __restrict__ mid) {
    __shared__ float sp[8 * 128];  // 4 KB
    int t = threadIdx.x;
    int base = blockIdx.x * 8;
    for (int i = t; i < 8 * 128; i += 256) sp[i] = pooled[base * 128 + i];
    __syncthreads();
    float acc[8] = {0.f, 0.f, 0.f, 0.f, 0.f, 0.f, 0.f, 0.f};
    for (int c = 0; c < 128; ++c) {
        float w = W[c * 256 + t];
#pragma unroll
        for (int gl = 0; gl < 8; ++gl) acc[gl] += sp[gl * 128 + c] * w;
    }
    float bb = bias[t];
#pragma unroll
    for (int gl = 0; gl < 8; ++gl) mid[(base + gl) * 256 + t] = fmaxf(acc[gl] + bb, 0.f);
}

// ---- lin2: out = mid @ lin2_W + b, 16 graphs/block ----
__global__ __launch_bounds__(128) void k_lin2(const float* __restrict__ mid,
                                              const float* __restrict__ W,
                                              const float* __restrict__ bias,
                                              float* __restrict__ out) {
    __shared__ float sm[16 * 256];  // 16 KB
    int t = threadIdx.x;
    int base = blockIdx.x * 16;
    for (int i = t; i < 16 * 256; i += 128) sm[i] = mid[base * 256 + i];
    __syncthreads();
    float acc[16];
#pragma unroll
    for (int i = 0; i < 16; ++i) acc[i] = 0.f;
    for (int c = 0; c < 256; ++c) {
        float w = W[c * 128 + t];
#pragma unroll
        for (int gl = 0; gl < 16; ++gl) acc[gl] += sm[gl * 256 + c] * w;
    }
    float bb = bias[t];
#pragma unroll
    for (int gl = 0; gl < 16; ++gl)
        out[(base + gl) * 128 + t] = acc[gl] + bb;
}

extern "C" void kernel_launch(void* const* d_in, const int* in_sizes, int n_in,
                              void* d_out, int out_size, void* d_ws, size_t ws_size,
                              hipStream_t stream) {
    (void)in_sizes; (void)n_in; (void)out_size; (void)ws_size;
    const float* x   = (const float*)d_in[0];
    const int* ei    = (const int*)d_in[1];
    const int* src = ei;
    const int* dst = ei + NE;
    const int* batch = (const int*)d_in[2];
    const float* nw  = (const float*)d_in[3];
    const float* nb  = (const float*)d_in[4];
    const float* W1  = (const float*)d_in[5];
    const float* b1  = (const float*)d_in[6];
    const float* W2  = (const float*)d_in[7];
    const float* b2  = (const float*)d_in[8];
    const float* W3  = (const float*)d_in[9];
    const float* b3  = (const float*)d_in[10];
    const float* l1W = (const float*)d_in[11];
    const float* l1b = (const float*)d_in[12];
    const float* l2W = (const float*)d_in[13];
    const float* l2b = (const float*)d_in[14];
    float* out = (float*)d_out;

    char* wsp = (char*)d_ws;
    int*   cnt      = (int*)wsp;   wsp += (size_t)NN * 4;        // becomes dis (float) in place
    int*   rowstart = (int*)wsp;   wsp += (size_t)(NN + 1) * 4;
    int*   cursor   = (int*)wsp;   wsp += (size_t)NN * 4;
    int*   bsum     = (int*)wsp;   wsp += (size_t)NBS * 4;
    int*   bpre     = (int*)wsp;   wsp += (size_t)NBS * 4;
    int*   startg   = (int*)wsp;   wsp += (size_t)(NG + 1) * 4;
    wsp += ((256 - ((uintptr_t)wsp & 255)) & 255);
    float* scale  = (float*)wsp; wsp += (size_t)NG * 128 * 4;    // later: pooled
    float* shift  = (float*)wsp; wsp += (size_t)NG * 128 * 4;    // later: csr (3.2 MB <= 4 MB)
    float* regionA = (float*)wsp; wsp += (size_t)NN * 64 * 4;    // p1|p2, later p3, later mid
    float* regionB = (float*)wsp; wsp += (size_t)NN * 64 * 4;    // a2, later a3

    float* dis  = (float*)cnt;  // in-place after k_dis
    float* p1   = regionA;
    float* p2   = regionA + (size_t)NN * 32;
    float* a2   = regionB;
    float* p3   = regionA;
    float* a3   = regionB;
    float* pooled = scale;      // scale dead after k_conv1
    int*   csr  = (int*)shift;  // shift dead after k_conv1 (fill runs after conv1)
    float* mid  = regionA;      // p3 dead after k_gather3

    // CSR prep (part 1: histogram + scan; cnt still int here)
    hipMemsetAsync(cnt, 0, (size_t)NN * 4, stream);
    k_cnt<<<(NE + 255) / 256, 256, 0, stream>>>(dst, cnt);
    k_blocksum<<<NBS, 256, 0, stream>>>(cnt, bsum);
    k_scanb<<<1, 1024, 0, stream>>>(bsum, bpre);
    k_scanchunk<<<NBS, 256, 0, stream>>>(cnt, bpre, rowstart);
    k_dis<<<(NN + 255) / 256, 256, 0, stream>>>(cnt);  // cnt -> dis in place
    hipMemcpyAsync(cursor, rowstart, (size_t)NN * 4, hipMemcpyDeviceToDevice, stream);

    // instance-norm + conv1 (uses scale/shift before csr overlays shift)
    k_starts<<<(NN + 255) / 256, 256, 0, stream>>>(batch, startg);
    k_stats<<<NG, 128, 0, stream>>>(x, startg, nw, nb, scale, shift);
    k_conv1<<<NN / 32, 256, 0, stream>>>(x, batch, scale, shift, W1, dis, p1);

    // CSR prep (part 2: fill into dead shift region)
    k_fill<<<(NE + 255) / 256, 256, 0, stream>>>(src, dst, cursor, csr);

    // layer 1 aggregation + epilogue
    k_gather1<<<NN * 32 / 256, 256, 0, stream>>>(p1, rowstart, csr, dis, b1, p2);
    // layer 2
    k_gather2<<<NN * 32 / 256, 256, 0, stream>>>(p2, rowstart, csr, dis, a2);
    k_conv2<<<NN / 16, 256, 0, stream>>>(a2, dis, W2, b2, p3);
    // layer 3
    k_gather3<<<NN * 64 / 256, 256, 0, stream>>>(p3, rowstart, csr, dis, a3);
    hipMemsetAsync(pooled, 0, (size_t)NG * 128 * 4, stream);
    k_conv3<<<NN / 8, 256, 0, stream>>>(a3, W3, b3, batch, (unsigned int*)pooled);

    // head
    k_lin1<<<NG / 8, 256, 0, stream>>>(pooled, l1W, l1b, mid);
    k_lin2<<<NG / 16, 128, 0, stream>>>(mid, l2W, l2b, out);
}

// Round 4
// 661.415 us; speedup vs baseline: 1.5029x; 1.0307x over previous
//
#include <hip/hip_runtime.h>
#include <stdint.h>

#define NN 200000
#define NE 800000
#define FIN 128
#define NG 8000
#define EPSV 1e-5f
#define NBS ((NN + 255) / 256)   // 782 scan blocks

// ---- int degree histogram over dst ----
__global__ void k_cnt(const int* __restrict__ dst, int* __restrict__ cnt) {
    int e = blockIdx.x * 256 + threadIdx.x;
    if (e < NE) atomicAdd(&cnt[dst[e]], 1);
}

// ---- per-256-chunk sums ----
__global__ void k_blocksum(const int* __restrict__ cnt, int* __restrict__ bsum) {
    __shared__ int sh[256];
    int b = blockIdx.x, t = threadIdx.x;
    int idx = b * 256 + t;
    sh[t] = (idx < NN) ? cnt[idx] : 0;
    __syncthreads();
    for (int o = 128; o > 0; o >>= 1) {
        if (t < o) sh[t] += sh[t + o];
        __syncthreads();
    }
    if (t == 0) bsum[b] = sh[0];
}

// ---- single-block scan of chunk sums -> exclusive prefixes ----
__global__ __launch_bounds__(1024) void k_scanb(const int* __restrict__ bsum, int* __restrict__ bpre) {
    __shared__ int sh[1024];
    int t = threadIdx.x;
    int v = (t < NBS) ? bsum[t] : 0;
    sh[t] = v;
    __syncthreads();
    for (int o = 1; o < 1024; o <<= 1) {
        int add = (t >= o) ? sh[t - o] : 0;
        __syncthreads();
        sh[t] += add;
        __syncthreads();
    }
    if (t < NBS) bpre[t] = sh[t] - v;  // exclusive
}

// ---- per-chunk scan + offset -> rowstart (exclusive) ----
__global__ void k_scanchunk(const int* __restrict__ cnt, const int* __restrict__ bpre,
                            int* __restrict__ rowstart) {
    __shared__ int sh[256];
    int b = blockIdx.x, t = threadIdx.x;
    int idx = b * 256 + t;
    int v = (idx < NN) ? cnt[idx] : 0;
    sh[t] = v;
    __syncthreads();
    for (int o = 1; o < 256; o <<= 1) {
        int add = (t >= o) ? sh[t - o] : 0;
        __syncthreads();
        sh[t] += add;
        __syncthreads();
    }
    if (idx < NN) rowstart[idx] = bpre[b] + sh[t] - v;
    if (idx == 0) rowstart[NN] = NE;
}

// ---- dis = rsqrt(1+deg), IN PLACE over cnt (int -> float reinterpret) ----
__global__ void k_dis(int* __restrict__ cnt) {
    int n = blockIdx.x * 256 + threadIdx.x;
    if (n < NN) {
        float d = rsqrtf(1.0f + (float)cnt[n]);
        ((float*)cnt)[n] = d;
    }
}

// ---- fill CSR: csr[pos] = src, bucketed by dst ----
__global__ void k_fill(const int* __restrict__ src, const int* __restrict__ dst,
                       int* __restrict__ cursor, int* __restrict__ csr) {
    int e = blockIdx.x * 256 + threadIdx.x;
    if (e < NE) {
        int pos = atomicAdd(&cursor[dst[e]], 1);
        csr[pos] = src[e];
    }
}

// ---- graph start offsets from sorted batch ----
__global__ void k_starts(const int* __restrict__ batch, int* __restrict__ startg) {
    int n = blockIdx.x * 256 + threadIdx.x;
    if (n >= NN) return;
    int b = batch[n];
    int prev = (n == 0) ? -1 : batch[n - 1];
    for (int g = prev + 1; g <= b; ++g) startg[g] = n;
    if (n == NN - 1) {
        for (int g = b + 1; g <= NG; ++g) startg[g] = NN;
    }
}

// ---- fused instance-norm + conv1 (one block per graph):
//      p1 = ((x - mean)*istd*w + b) @ W1 * dis   [128 -> 32] ----
__global__ __launch_bounds__(256) void k_norm_conv1(const float* __restrict__ x,
                                                    const int* __restrict__ startg,
                                                    const float* __restrict__ nw,
                                                    const float* __restrict__ nb,
                                                    const float* __restrict__ W1,
                                                    const float* __restrict__ dis,
                                                    float* __restrict__ p1) {
    __shared__ float sW[FIN * 32];    // 16 KB
    __shared__ float ssum[256], ssq[256];
    __shared__ float sscale[FIN], sshift[FIN];
    __shared__ float sx[8 * FIN];     // 4 KB
    int g = blockIdx.x;
    int s = startg[g], e = startg[g + 1];
    if (s == e) return;
    int t = threadIdx.x;
    const float4* W4 = (const float4*)W1;
    for (int i = t; i < FIN * 32 / 4; i += 256) ((float4*)sW)[i] = W4[i];
    // stats: 2 slots x 128 channels
    {
        int c = t & 127, slot = t >> 7;
        float sum = 0.f, sq = 0.f;
        for (int n = s + slot; n < e; n += 2) {
            float v = x[n * FIN + c];
            sum += v; sq += v * v;
        }
        ssum[t] = sum; ssq[t] = sq;
    }
    __syncthreads();
    if (t < 128) {
        float sm = ssum[t] + ssum[t + 128];
        float q2 = ssq[t] + ssq[t + 128];
        float cntf = (float)(e - s);
        float mean = sm / cntf;
        float var = q2 / cntf - mean * mean;
        float istd = rsqrtf(fmaxf(var, 0.f) + EPSV);
        float w = nw[0], b = nb[0];
        sscale[t] = istd * w;
        sshift[t] = b - mean * istd * w;
    }
    const float4* x4 = (const float4*)x;
    int k = t & 31, mslot = t >> 5;           // 8 node slots
    int row = t >> 5, c4 = t & 31;            // staging role
    for (int cb = s; cb < e; cb += 8) {
        __syncthreads();  // sscale ready (1st iter) / sx safe to overwrite
        int n = cb + row;
        if (n < e) {
            float4 xv = x4[n * 32 + c4];
            float4 r;
            r.x = xv.x * sscale[c4 * 4 + 0] + sshift[c4 * 4 + 0];
            r.y = xv.y * sscale[c4 * 4 + 1] + sshift[c4 * 4 + 1];
            r.z = xv.z * sscale[c4 * 4 + 2] + sshift[c4 * 4 + 2];
            r.w = xv.w * sscale[c4 * 4 + 3] + sshift[c4 * 4 + 3];
            ((float4*)sx)[row * 32 + c4] = r;
        }
        __syncthreads();
        int nm = cb + mslot;
        if (nm < e) {
            float acc = 0.f;
            for (int cc = 0; cc < FIN; ++cc) acc += sx[mslot * FIN + cc] * sW[cc * 32 + k];
            p1[nm * 32 + k] = acc * dis[nm];
        }
    }
}

// ---- gather1 (C=32, float4) + conv1 epilogue: p2 = relu(dis*(self+neigh)+b1)*dis ----
__global__ __launch_bounds__(256) void k_gather1(const float* __restrict__ p1,
                                                 const int* __restrict__ rowstart,
                                                 const int* __restrict__ csr,
                                                 const float* __restrict__ dis,
                                                 const float* __restrict__ b1,
                                                 float* __restrict__ p2) {
    int tid = blockIdx.x * 256 + threadIdx.x;  // NN*8 threads
    int n = tid >> 3, c4 = tid & 7;
    const float4* p1_4 = (const float4*)p1;
    int s = rowstart[n], e = rowstart[n + 1];
    float4 agg = p1_4[n * 8 + c4];  // self-loop (p = h*dis already)
    int j = s;
    for (; j + 1 < e; j += 2) {
        float4 v0 = p1_4[csr[j] * 8 + c4];
        float4 v1 = p1_4[csr[j + 1] * 8 + c4];
        agg.x += v0.x + v1.x; agg.y += v0.y + v1.y;
        agg.z += v0.z + v1.z; agg.w += v0.w + v1.w;
    }
    if (j < e) {
        float4 v = p1_4[csr[j] * 8 + c4];
        agg.x += v.x; agg.y += v.y; agg.z += v.z; agg.w += v.w;
    }
    float d = dis[n];
    float4 bb = ((const float4*)b1)[c4];
    float4 r;
    r.x = fmaxf(d * agg.x + bb.x, 0.f) * d;
    r.y = fmaxf(d * agg.y + bb.y, 0.f) * d;
    r.z = fmaxf(d * agg.z + bb.z, 0.f) * d;
    r.w = fmaxf(d * agg.w + bb.w, 0.f) * d;
    ((float4*)p2)[n * 8 + c4] = r;
}

// ---- fused gather2 + conv2: p3 = relu((dis*(self+neigh))@W2 + b2)*dis  [32->64], 16 nodes/block ----
__global__ __launch_bounds__(256) void k_conv2g(const float* __restrict__ p2,
                                                const int* __restrict__ rowstart,
                                                const int* __restrict__ csr,
                                                const float* __restrict__ dis,
                                                const float* __restrict__ W2,
                                                const float* __restrict__ b2v,
                                                float* __restrict__ p3) {
    __shared__ float sW[32 * 64];        // 8 KB
    __shared__ float4 spart[16 * 16];    // 16 nodes x 2 halves x 8 c4 = 4 KB
    __shared__ float sa[16 * 32];        // 2 KB
    int t = threadIdx.x;
    const float4* W4 = (const float4*)W2;
    for (int i = t; i < 32 * 64 / 4; i += 256) ((float4*)sW)[i] = W4[i];
    int base = blockIdx.x * 16;
    const float4* p2_4 = (const float4*)p2;
    {
        int node = t >> 4, c4 = t & 7, half = (t >> 3) & 1;
        int n = base + node;
        int s = rowstart[n], e = rowstart[n + 1];
        float4 agg = {0.f, 0.f, 0.f, 0.f};
        if (half == 0) {
            agg = p2_4[n * 8 + c4];  // self
            for (int j = s; j < e; j += 2) {
                float4 v = p2_4[csr[j] * 8 + c4];
                agg.x += v.x; agg.y += v.y; agg.z += v.z; agg.w += v.w;
            }
        } else {
            for (int j = s + 1; j < e; j += 2) {
                float4 v = p2_4[csr[j] * 8 + c4];
                agg.x += v.x; agg.y += v.y; agg.z += v.z; agg.w += v.w;
            }
        }
        spart[node * 16 + half * 8 + c4] = agg;
    }
    __syncthreads();
    if (t < 128) {
        int nd = t >> 3, cc = t & 7;
        float4 a = spart[nd * 16 + cc], b = spart[nd * 16 + 8 + cc];
        float d = dis[base + nd];
        float4 r;
        r.x = d * (a.x + b.x); r.y = d * (a.y + b.y);
        r.z = d * (a.z + b.z); r.w = d * (a.w + b.w);
        ((float4*)sa)[nd * 8 + cc] = r;
    }
    __syncthreads();
    int k = t & 63, grp = t >> 6;
    float acc[4] = {0.f, 0.f, 0.f, 0.f};
    for (int c = 0; c < 32; ++c) {
        float w = sW[c * 64 + k];
#pragma unroll
        for (int q = 0; q < 4; ++q) acc[q] += sa[(grp * 4 + q) * 32 + c] * w;
    }
    float bb = b2v[k];
#pragma unroll
    for (int q = 0; q < 4; ++q) {
        int n = base + grp * 4 + q;
        float h = fmaxf(acc[q] + bb, 0.f);
        p3[n * 64 + k] = h * dis[n];
    }
}

// ---- fused gather3 + conv3 + max-pool (one block per graph), zero atomics ----
__global__ __launch_bounds__(256) void k_conv3g(const float* __restrict__ p3,
                                                const int* __restrict__ rowstart,
                                                const int* __restrict__ csr,
                                                const float* __restrict__ dis,
                                                const float* __restrict__ W3,
                                                const float* __restrict__ b3v,
                                                const int* __restrict__ startg,
                                                float* __restrict__ pooled) {
    __shared__ float sW[64 * 128];       // 32 KB
    __shared__ float4 spart[8 * 32];     // 8 nodes x 2 halves x 16 c4 = 4 KB
    __shared__ float sa[8 * 64];         // 2 KB
    __shared__ float smax[256];
    int g = blockIdx.x;
    int s = startg[g], e = startg[g + 1];
    int t = threadIdx.x;
    if (s == e) {
        if (t < 128) pooled[g * 128 + t] = 0.f;
        return;
    }
    const float4* W4 = (const float4*)W3;
    for (int i = t; i < 64 * 128 / 4; i += 256) ((float4*)sW)[i] = W4[i];
    const float4* p3_4 = (const float4*)p3;
    int k = t & 127, hslot = t >> 7;
    int gnode = t >> 5, gc4 = t & 15, ghalf = (t >> 4) & 1;
    float bb = b3v[k];
    float mx = 0.f;
    for (int cb = s; cb < e; cb += 8) {
        __syncthreads();  // sW ready (1st iter) / sa,spart safe to overwrite
        {
            int n = cb + gnode;
            float4 agg = {0.f, 0.f, 0.f, 0.f};
            if (n < e) {
                int rs = rowstart[n], re = rowstart[n + 1];
                if (ghalf == 0) {
                    agg = p3_4[n * 16 + gc4];  // self
                    for (int j = rs; j < re; j += 2) {
                        float4 v = p3_4[csr[j] * 16 + gc4];
                        agg.x += v.x; agg.y += v.y; agg.z += v.z; agg.w += v.w;
                    }
                } else {
                    for (int j = rs + 1; j < re; j += 2) {
                        float4 v = p3_4[csr[j] * 16 + gc4];
                        agg.x += v.x; agg.y += v.y; agg.z += v.z; agg.w += v.w;
                    }
                }
            }
            spart[gnode * 32 + ghalf * 16 + gc4] = agg;
        }
        __syncthreads();
        if (t < 128) {
            int nd = t >> 4, cc = t & 15;
            float4 a = spart[nd * 32 + cc], b = spart[nd * 32 + 16 + cc];
            float dn = (cb + nd < e) ? dis[cb + nd] : 0.f;
            float4 r;
            r.x = dn * (a.x + b.x); r.y = dn * (a.y + b.y);
            r.z = dn * (a.z + b.z); r.w = dn * (a.w + b.w);
            ((float4*)sa)[nd * 16 + cc] = r;
        }
        __syncthreads();
        int lim = e - cb;
        float acc[4] = {0.f, 0.f, 0.f, 0.f};
        for (int c = 0; c < 64; ++c) {
            float w = sW[c * 128 + k];
#pragma unroll
            for (int q = 0; q < 4; ++q) acc[q] += sa[(hslot * 4 + q) * 64 + c] * w;
        }
#pragma unroll
        for (int q = 0; q < 4; ++q) {
            if (hslot * 4 + q < lim) mx = fmaxf(mx, acc[q] + bb);
        }
    }
    smax[t] = mx;
    __syncthreads();
    if (t < 128) pooled[g * 128 + t] = fmaxf(fmaxf(smax[t], smax[t + 128]), 0.f);
}

// ---- lin1: mid = relu(pooled @ lin1_W + b), 8 graphs/block ----
__global__ __launch_bounds__(256) void k_lin1(const float* __restrict__ pooled,
                                              const float* __restrict__ W,
                                              const float* __restrict__ bias,
                                              float* __restrict__ mid) {
    __shared__ float sp[8 * 128];  // 4 KB
    int t = threadIdx.x;
    int base = blockIdx.x * 8;
    for (int i = t; i < 8 * 128; i += 256) sp[i] = pooled[base * 128 + i];
    __syncthreads();
    float acc[8] = {0.f, 0.f, 0.f, 0.f, 0.f, 0.f, 0.f, 0.f};
    for (int c = 0; c < 128; ++c) {
        float w = W[c * 256 + t];
#pragma unroll
        for (int gl = 0; gl < 8; ++gl) acc[gl] += sp[gl * 128 + c] * w;
    }
    float bb = bias[t];
#pragma unroll
    for (int gl = 0; gl < 8; ++gl) mid[(base + gl) * 256 + t] = fmaxf(acc[gl] + bb, 0.f);
}

// ---- lin2: out = mid @ lin2_W + b, 16 graphs/block ----
__global__ __launch_bounds__(128) void k_lin2(const float* __restrict__ mid,
                                              const float* __restrict__ W,
                                              const float* __restrict__ bias,
                                              float* __restrict__ out) {
    __shared__ float sm[16 * 256];  // 16 KB
    int t = threadIdx.x;
    int base = blockIdx.x * 16;
    for (int i = t; i < 16 * 256; i += 128) sm[i] = mid[base * 256 + i];
    __syncthreads();
    float acc[16];
#pragma unroll
    for (int i = 0; i < 16; ++i) acc[i] = 0.f;
    for (int c = 0; c < 256; ++c) {
        float w = W[c * 128 + t];
#pragma unroll
        for (int gl = 0; gl < 16; ++gl) acc[gl] += sm[gl * 256 + c] * w;
    }
    float bb = bias[t];
#pragma unroll
    for (int gl = 0; gl < 16; ++gl)
        out[(base + gl) * 128 + t] = acc[gl] + bb;
}

extern "C" void kernel_launch(void* const* d_in, const int* in_sizes, int n_in,
                              void* d_out, int out_size, void* d_ws, size_t ws_size,
                              hipStream_t stream) {
    (void)in_sizes; (void)n_in; (void)out_size; (void)ws_size;
    const float* x   = (const float*)d_in[0];
    const int* ei    = (const int*)d_in[1];
    const int* src = ei;
    const int* dst = ei + NE;
    const int* batch = (const int*)d_in[2];
    const float* nw  = (const float*)d_in[3];
    const float* nb  = (const float*)d_in[4];
    const float* W1  = (const float*)d_in[5];
    const float* b1  = (const float*)d_in[6];
    const float* W2  = (const float*)d_in[7];
    const float* b2  = (const float*)d_in[8];
    const float* W3  = (const float*)d_in[9];
    const float* b3  = (const float*)d_in[10];
    const float* l1W = (const float*)d_in[11];
    const float* l1b = (const float*)d_in[12];
    const float* l2W = (const float*)d_in[13];
    const float* l2b = (const float*)d_in[14];
    float* out = (float*)d_out;

    char* wsp = (char*)d_ws;
    int*   cnt      = (int*)wsp;   wsp += (size_t)NN * 4;        // becomes dis in place
    int*   rowstart = (int*)wsp;   wsp += (size_t)(NN + 1) * 4;
    int*   cursor   = (int*)wsp;   wsp += (size_t)NN * 4;
    int*   bsum     = (int*)wsp;   wsp += (size_t)NBS * 4;
    int*   bpre     = (int*)wsp;   wsp += (size_t)NBS * 4;
    int*   startg   = (int*)wsp;   wsp += (size_t)(NG + 1) * 4;
    int*   csr      = (int*)wsp;   wsp += (size_t)NE * 4;        // 3.2 MB
    wsp += ((256 - ((uintptr_t)wsp & 255)) & 255);
    float* pooled  = (float*)wsp; wsp += (size_t)NG * 128 * 4;   // 4 MB
    float* regionA = (float*)wsp; wsp += (size_t)NN * 64 * 4;    // p1|p2, later mid
    float* regionB = (float*)wsp; wsp += (size_t)NN * 64 * 4;    // p3

    float* dis  = (float*)cnt;  // in-place after k_dis
    float* p1   = regionA;
    float* p2   = regionA + (size_t)NN * 32;
    float* p3   = regionB;
    float* mid  = regionA;      // p1/p2 dead after k_conv2g

    // CSR prep
    hipMemsetAsync(cnt, 0, (size_t)NN * 4, stream);
    k_cnt<<<(NE + 255) / 256, 256, 0, stream>>>(dst, cnt);
    k_blocksum<<<NBS, 256, 0, stream>>>(cnt, bsum);
    k_scanb<<<1, 1024, 0, stream>>>(bsum, bpre);
    k_scanchunk<<<NBS, 256, 0, stream>>>(cnt, bpre, rowstart);
    k_dis<<<(NN + 255) / 256, 256, 0, stream>>>(cnt);  // cnt -> dis in place
    hipMemcpyAsync(cursor, rowstart, (size_t)NN * 4, hipMemcpyDeviceToDevice, stream);
    k_fill<<<(NE + 255) / 256, 256, 0, stream>>>(src, dst, cursor, csr);

    // layer 1
    k_starts<<<(NN + 255) / 256, 256, 0, stream>>>(batch, startg);
    k_norm_conv1<<<NG, 256, 0, stream>>>(x, startg, nw, nb, W1, dis, p1);
    k_gather1<<<NN * 8 / 256, 256, 0, stream>>>(p1, rowstart, csr, dis, b1, p2);
    // layer 2 (fused gather+matmul)
    k_conv2g<<<NN / 16, 256, 0, stream>>>(p2, rowstart, csr, dis, W2, b2, p3);
    // layer 3 (fused gather+matmul+pool)
    k_conv3g<<<NG, 256, 0, stream>>>(p3, rowstart, csr, dis, W3, b3, startg, pooled);

    // head
    k_lin1<<<NG / 8, 256, 0, stream>>>(pooled, l1W, l1b, mid);
    k_lin2<<<NG / 16, 128, 0, stream>>>(mid, l2W, l2b, out);
}